// Round 7
// baseline (240.058 us; speedup 1.0000x reference)
//
#include <hip/hip_runtime.h>
#include <hip/hip_cooperative_groups.h>
#include <math.h>

namespace cg = cooperative_groups;

#define B 4
#define P (512*1024)        // 524288 px per batch image
#define NI 8
#define NSEG 32             // seg = n*B + b
#define NB 1024             // histogram buckets over err in [0,2]
#define INV_BW 512.0f       // NB/2
#define NCHUNK 64
#define CHUNK_PX 8192
#define NBLK 256            // 1 block per CU -> cooperative launch always fits
#define NTHR 512

// ---- ws layout (4-byte units) ----
#define D_CENY 0
#define D_CENX 32
#define D_PSY  64
#define D_PSX  96
#define D_CNT  128
#define D_SL   160
#define D_BGL  192                        // 4
#define OFF_PK1  256                      // 256*64 f = 64 KB
#define OFF_FGP  (OFF_PK1 + NBLK*64)      // NSEG*NCHUNK f = 8 KB
#define OFF_FOLD (OFF_FGP + NSEG*NCHUNK)  // 2*NSEG*NB u32 = 256 KB
#define OFF_HIST (OFF_FOLD + 2*NSEG*NB)   // NSEG*NCHUNK*NB u32 = 8 MB

__device__ __forceinline__ float fast_tanh(float x) {
    float e = __expf(2.0f * x);
    return 1.0f - 2.0f / (e + 1.0f);
}
__device__ __forceinline__ float fast_sigmoid(float x) {
    return 1.0f / (1.0f + __expf(-x));
}
template<int CTRL, int RM>
__device__ __forceinline__ float dpp_add(float x) {
    int y = __builtin_amdgcn_update_dpp(0, __float_as_int(x), CTRL, RM, 0xF, true);
    return x + __int_as_float(y);
}
__device__ __forceinline__ float wred(float x) {
    x = dpp_add<0x111, 0xF>(x);   // row_shr:1
    x = dpp_add<0x112, 0xF>(x);   // row_shr:2
    x = dpp_add<0x114, 0xF>(x);   // row_shr:4
    x = dpp_add<0x118, 0xF>(x);   // row_shr:8
    x = dpp_add<0x142, 0xA>(x);   // row_bcast:15
    x = dpp_add<0x143, 0xC>(x);   // row_bcast:31
    return x;                     // lane 63 = wave total
}

__global__ __launch_bounds__(NTHR, 2) void fused_all(const float* __restrict__ xv,
                                                     const float* __restrict__ xs,
                                                     const float* __restrict__ xseed,
                                                     const int*  __restrict__ t,
                                                     float* __restrict__ wsf,
                                                     unsigned* __restrict__ hist_g,
                                                     float* __restrict__ out) {
    cg::grid_group grid = cg::this_grid();
    const int bid = blockIdx.x;
    const int c   = bid >> 2;          // chunk 0..63
    const int b   = bid & 3;
    const int tid = threadIdx.x;
    const int lane = tid & 63, wid = tid >> 6;   // wid 0..7

    __shared__ unsigned shm[NI*NB];    // 32 KB, reused every phase
    __shared__ float sw[8*64];         // phase A wave partials (2 KB)
    __shared__ float sfg8[NI];
    __shared__ float scnt32[NSEG];

    float* pk1 = wsf + OFF_PK1;
    float* fgp = wsf + OFF_FGP;
    unsigned* fold = (unsigned*)wsf + OFF_FOLD;

    // register stash across phases: 16 px/thread
    float eys[16], exs[16], ssg[16];
    unsigned tvp[2] = {0u, 0u};

    // ================= Phase A: stats =================
    {
        const float* xv_y = xv + (size_t)b*2*P;
        const float* xv_x = xv_y + P;
        const float* xs_y = xs + (size_t)b*2*P;
        const float* xs_x = xs_y + P;
        const float* sdp  = xseed + (size_t)b*P;
        const int*   tb   = t + (size_t)b*P;
        const int base = c * CHUNK_PX;

        float cnt[NI], sey[NI], sex[NI], sgy[NI], sgx[NI], sq[NI];
        #pragma unroll
        for (int n = 0; n < NI; ++n) { cnt[n]=0.f; sey[n]=0.f; sex[n]=0.f; sgy[n]=0.f; sgx[n]=0.f; sq[n]=0.f; }
        float bgc = 0.f, bgs = 0.f;

        #pragma unroll
        for (int it = 0; it < 4; ++it) {
            int p0 = base + it*2048 + tid*4;
            float4 vy = *(const float4*)(xv_y + p0);
            float4 vx = *(const float4*)(xv_x + p0);
            float4 sy = *(const float4*)(xs_y + p0);
            float4 sx = *(const float4*)(xs_x + p0);
            float4 se = *(const float4*)(sdp + p0);
            int4   tt = *(const int4*)(tb + p0);
            #pragma unroll
            for (int j = 0; j < 4; ++j) {
                int idx = it*4 + j;
                int pix = p0 + j;
                float ey = fast_tanh((&vy.x)[j]) + (float)(pix >> 10) * (1.0f/1024.0f);
                float ex = fast_tanh((&vx.x)[j]) + (float)(pix & 1023) * (1.0f/1024.0f);
                float gy = (&sy.x)[j], gx = (&sx.x)[j];
                float s  = fast_sigmoid((&se.x)[j]);
                int tv = (&tt.x)[j];
                eys[idx] = ey; exs[idx] = ex; ssg[idx] = s;
                tvp[idx >> 3] |= ((unsigned)tv) << ((idx & 7)*4);
                if (tv == 0) { bgc += 1.f; bgs += s*s; }
                float q = gy*gy + gx*gx;
                #pragma unroll
                for (int n = 0; n < NI; ++n) {
                    float m = (tv == n+1) ? 1.0f : 0.0f;
                    cnt[n] += m; sey[n] += m*ey; sex[n] += m*ex;
                    sgy[n] += m*gy; sgx[n] += m*gx; sq[n] += m*q;
                }
            }
        }
        #define RED50(val, slot) { float r_ = wred(val); if (lane == 63) sw[wid*64 + (slot)] = r_; }
        #pragma unroll
        for (int n = 0; n < NI; ++n) {
            RED50(cnt[n], n*6+0); RED50(sey[n], n*6+1); RED50(sex[n], n*6+2);
            RED50(sgy[n], n*6+3); RED50(sgx[n], n*6+4); RED50(sq[n],  n*6+5);
        }
        RED50(bgc, 48); RED50(bgs, 49);
        #undef RED50
        __syncthreads();
        if (tid < 50) {
            float s = 0.f;
            #pragma unroll
            for (int w = 0; w < 8; ++w) s += sw[w*64 + tid];
            pk1[(size_t)bid*64 + tid] = s;
        }
    }
    grid.sync();

    // ================= Phase B: finalize params (block 0) =================
    if (bid == 0) {
        float* part = (float*)shm;               // 8*64 floats
        const int v = tid & 63, g = tid >> 6;    // g 0..7
        const int bb = g & 3, h = g >> 2;        // half-range per batch
        float acc = 0.f;
        #pragma unroll 8
        for (int i = 0; i < 32; ++i) {
            int cc = h*32 + i;
            acc += pk1[(size_t)(cc*4 + bb)*64 + v];
        }
        part[g*64 + v] = acc;
        __syncthreads();
        if (tid < 256) {
            int b2 = tid >> 6, v2 = tid & 63;
            part[b2*64 + v2] = part[b2*64 + v2] + part[(b2+4)*64 + v2];
        }
        __syncthreads();
        if (tid < NSEG) {
            int n = tid >> 2, b2 = tid & 3;      // seg = n*B + b2 = tid
            float cv  = part[b2*64 + n*6+0];
            float sey = part[b2*64 + n*6+1];
            float sex = part[b2*64 + n*6+2];
            float sgy = part[b2*64 + n*6+3];
            float sgx = part[b2*64 + n*6+4];
            float sq  = part[b2*64 + n*6+5];
            float safe = fmaxf(cv, 1.0f);
            float ipy = sgy/safe, ipx = sgx/safe;
            wsf[D_CENY+tid] = sey/safe;
            wsf[D_CENX+tid] = sex/safe;
            wsf[D_PSY+tid]  = expf(10.0f*ipy);
            wsf[D_PSX+tid]  = expf(10.0f*ipx);
            wsf[D_CNT+tid]  = cv;
            wsf[D_SL+tid]   = sq/safe - (ipy*ipy + ipx*ipx);
        } else if (tid < NSEG + B) {
            int b2 = tid - NSEG;
            wsf[D_BGL+b2] = part[b2*64+49] / fmaxf(part[b2*64+48], 1.0f);
        } else if (tid == 40) {
            out[0] = 0.f;
        }
    }
    grid.sync();

    // ================= Phase C: LDS histograms from register stash =================
    {
        for (int i = tid; i < NI*NB; i += NTHR) shm[i] = 0u;
        float ceny[NI], cenx[NI], psy[NI], psx[NI], fgn[NI];
        #pragma unroll
        for (int n = 0; n < NI; ++n) {
            ceny[n] = wsf[D_CENY + n*4 + b];
            cenx[n] = wsf[D_CENX + n*4 + b];
            psy[n]  = wsf[D_PSY  + n*4 + b];
            psx[n]  = wsf[D_PSX  + n*4 + b];
            fgn[n]  = 0.f;
        }
        if (tid < NI) sfg8[tid] = 0.f;
        __syncthreads();

        #pragma unroll
        for (int it = 0; it < 4; ++it) {
            #pragma unroll
            for (int j = 0; j < 4; ++j) {
                int idx = it*4 + j;
                float ey = eys[idx], ex = exs[idx];
                int tv = (int)((tvp[idx >> 3] >> ((idx & 7)*4)) & 0xFu);
                float gown = 0.f;
                #pragma unroll
                for (int n = 0; n < NI; ++n) {
                    float dy = ey - ceny[n], dx = ex - cenx[n];
                    float g = __expf(-0.5f * (psy[n]*dy*dy + psx[n]*dx*dx));
                    bool lab = (tv == n+1);
                    float err = lab ? (2.0f - 2.0f*g) : (2.0f*g);
                    int key = (int)(err * INV_BW);
                    key = key > (NB-1) ? (NB-1) : key;
                    // key==0 counts reconstructed exactly in phase E from totals
                    if (key > 0) atomicAdd(&shm[n*NB + key], lab ? 0x10000u : 1u);
                    if (lab) gown = g;
                }
                if (tv > 0) {
                    float d = ssg[idx] - gown;
                    float dd = d*d;
                    #pragma unroll
                    for (int n = 0; n < NI; ++n) fgn[n] += (tv == n+1) ? dd : 0.f;
                }
            }
        }
        __syncthreads();
        for (int i = tid; i < NI*NB; i += NTHR) {
            int n = i >> 10, key = i & (NB-1);
            hist_g[((size_t)((n*4 + b)*NCHUNK + c))*NB + key] = shm[i];
        }
        #pragma unroll
        for (int n = 0; n < NI; ++n) {
            float r = wred(fgn[n]);
            if (lane == 63 && r != 0.f) atomicAdd(&sfg8[n], r);
        }
        __syncthreads();
        if (tid < NI) fgp[(tid*4 + b)*NCHUNK + c] = sfg8[tid];
    }
    grid.sync();

    // ================= Phase D: wide fold (256 blocks) =================
    {
        const int seg = bid >> 3, kb = bid & 7;      // 8 keyblocks of 128 keys
        const int k = tid & 127, sh = tid >> 7;      // sh: chunk quarter 0..3
        const unsigned* src = hist_g + (size_t)(seg*NCHUNK)*NB + kb*128 + k;
        unsigned pos = 0u, neg = 0u;
        #pragma unroll 8
        for (int cc = sh*16; cc < sh*16 + 16; ++cc) {
            unsigned v = src[(size_t)cc*NB];         // coalesced across 128 threads
            pos += v >> 16; neg += v & 0xffffu;
        }
        if (tid < 256) shm[tid] = 0u;
        __syncthreads();
        atomicAdd(&shm[k], pos);
        atomicAdd(&shm[128 + k], neg);
        __syncthreads();
        if (tid < 128)      fold[(size_t)seg*NB + kb*128 + tid] = shm[tid];
        else if (tid < 256) fold[(size_t)(NSEG + seg)*NB + kb*128 + (tid-128)] = shm[tid];
    }
    grid.sync();

    // ================= Phase E: suffix scan + finalize (32 blocks) =================
    if (bid < NSEG) {
        const int seg = bid;
        const int bb = seg & 3;
        if (tid < NSEG) scnt32[tid] = wsf[D_CNT + tid];
        __syncthreads();

        if (seg == 0 && tid == 0) {   // sigma loss + background seed loss
            float add = 0.f;
            for (int b2 = 0; b2 < B; ++b2) {
                int np = 0; float ss = 0.f;
                for (int k = 0; k < NI; ++k) {
                    float cv = scnt32[k*4 + b2];
                    if (cv > 0.5f) { np++; ss += wsf[D_SL + k*4 + b2]; }
                }
                float npf = fmaxf((float)np, 1.0f);
                add += ss/npf + wsf[D_BGL+b2] / (1.0f + (float)np);
            }
            atomicAdd(out, add * (1.0f/(float)B));
        }

        const float G = scnt32[seg];
        if (G >= 0.5f) {
            int npc = 0;
            #pragma unroll
            for (int k = 0; k < NI; ++k) npc += (scnt32[k*4 + bb] > 0.5f) ? 1 : 0;

            float* sfr = (float*)(shm + 3072);   // 64 floats (clear of up/un/sdd)
            if (tid < NCHUNK) sfr[tid] = fgp[seg*NCHUNK + tid];
            __syncthreads();
            #pragma unroll
            for (int d = 32; d > 0; d >>= 1) {
                if (tid < d) sfr[tid] += sfr[tid + d];
                __syncthreads();
            }
            const float FG = sfr[0];

            // thread owns keys 2t, 2t+1
            uint2 pv = *((const uint2*)(fold + (size_t)seg*NB) + tid);
            uint2 nv = *((const uint2*)(fold + (size_t)(NSEG + seg)*NB) + tid);
            unsigned pos2[2] = {pv.x, pv.y};
            unsigned neg2[2] = {nv.x, nv.y};
            unsigned tp = pos2[0] + pos2[1];
            unsigned tn = neg2[0] + neg2[1];

            unsigned* up = shm;                   // 512
            unsigned* un = shm + 512;             // 512
            double* sdd = (double*)(shm + 1024);  // 512 doubles
            up[tid] = tp; un[tid] = tn;
            __syncthreads();
            for (int d = 1; d < NTHR; d <<= 1) {
                unsigned ap = (tid + d < NTHR) ? up[tid + d] : 0u;
                unsigned an = (tid + d < NTHR) ? un[tid + d] : 0u;
                __syncthreads();
                up[tid] += ap; un[tid] += an;
                __syncthreads();
            }
            const unsigned TP = up[0], TN = un[0];
            const unsigned Gu = (unsigned)(G + 0.5f);
            const unsigned NEGu = (unsigned)P - Gu;
            unsigned cump = up[tid] - tp;   // counts with key strictly greater
            unsigned cumn = un[tid] - tn;

            const double dG = (double)G;
            double acc = 0.0;
            #pragma unroll
            for (int j = 1; j >= 0; --j) {
                unsigned cp = pos2[j], cn = neg2[j];
                int key = tid*2 + j;
                if (tid == 0 && j == 0) { cp = Gu - TP; cn = NEGu - TN; }  // exact bucket-0
                if (cp | cn) {
                    unsigned ep = cump, en = cumn;
                    unsigned epi = ep + cp, eni = en + cn;
                    double jb = 1.0 - (dG - (double)ep)  / (dG + (double)en);
                    double ja = 1.0 - (dG - (double)epi) / (dG + (double)eni);
                    acc += (((double)key + 0.5) * (2.0/(double)NB)) * (ja - jb);
                }
                cump += cp; cumn += cn;
            }
            sdd[tid] = acc;
            __syncthreads();
            #pragma unroll
            for (int d = 256; d > 0; d >>= 1) {
                if (tid < d) sdd[tid] += sdd[tid + d];
                __syncthreads();
            }
            if (tid == 0) {
                float npf = fmaxf((float)npc, 1.0f);
                float val = (float)sdd[0] / (npf * (float)B)
                          + (FG / G) / ((1.0f + (float)npc) * (float)B);
                atomicAdd(out, val);
            }
        }
    }
}

extern "C" void kernel_launch(void* const* d_in, const int* in_sizes, int n_in,
                              void* d_out, int out_size, void* d_ws, size_t ws_size,
                              hipStream_t stream) {
    (void)in_sizes; (void)n_in; (void)out_size; (void)ws_size;
    const float* xv  = (const float*)d_in[0];
    const float* xs  = (const float*)d_in[1];
    const float* xsd = (const float*)d_in[2];
    const int*   t   = (const int*)d_in[3];
    float* wsf = (float*)d_ws;
    unsigned* hist_g = (unsigned*)d_ws + OFF_HIST;
    float* out = (float*)d_out;

    void* args[] = { (void*)&xv, (void*)&xs, (void*)&xsd, (void*)&t,
                     (void*)&wsf, (void*)&hist_g, (void*)&out };
    hipLaunchCooperativeKernel((const void*)fused_all, dim3(NBLK), dim3(NTHR),
                               args, 0, stream);
}

// Round 8
// 181.455 us; speedup vs baseline: 1.3230x; 1.3230x over previous
//
#include <hip/hip_runtime.h>
#include <math.h>

#define B 4
#define H 512
#define W 1024
#define P (H*W)            // 524288
#define NI 8
#define NSEG 32            // seg = n*B + b
#define NB 1024            // histogram buckets over err in [0,2]
#define INV_BW ((float)NB/2.0f)
#define NSTRIP 128
#define STRIP_PX (P/NSTRIP) // 4096
#define K1B 512             // k1 blocks per batch
#define K1PX (P/K1B)        // 1024 px per k1 block

// ---- ws layout (4-byte units) ----
#define D_CENY 0
#define D_CENX 32
#define D_PSY  64
#define D_PSX  96
#define D_CNT  128
#define D_SL   160
#define D_BGL  192          // 4
#define OFF_FGP 256         // NI*512 floats = 16 KB
#define OFF_HIST (256 + NI*512)              // u32: NSEG*NSTRIP*NB = 16 MB
#define OFF_FOLD (OFF_HIST + NSEG*NSTRIP*NB) // u32: 2*NSEG*NB = 256 KB
#define OFF_PK1  OFF_HIST   // pk1 (2048*64 floats = 512 KB) overlaps hist:
                            // k1 writes pk1 -> k2 consumes -> k3 overwrites hist. Safe.

__device__ __forceinline__ float fast_tanh(float x) {
    float e = __expf(2.0f * x);
    return 1.0f - 2.0f / (e + 1.0f);
}
__device__ __forceinline__ float fast_sigmoid(float x) {
    return 1.0f / (1.0f + __expf(-x));
}
template<int CTRL, int RM>
__device__ __forceinline__ float dpp_add(float x) {
    int y = __builtin_amdgcn_update_dpp(0, __float_as_int(x), CTRL, RM, 0xF, true);
    return x + __int_as_float(y);
}
__device__ __forceinline__ float wred(float x) {
    x = dpp_add<0x111, 0xF>(x);   // row_shr:1
    x = dpp_add<0x112, 0xF>(x);   // row_shr:2
    x = dpp_add<0x114, 0xF>(x);   // row_shr:4
    x = dpp_add<0x118, 0xF>(x);   // row_shr:8
    x = dpp_add<0x142, 0xA>(x);   // row_bcast:15
    x = dpp_add<0x143, 0xC>(x);   // row_bcast:31
    return x;                     // lane 63 = wave total
}

// ---------------- K1: per-block partials via per-wave LDS float atomics ----------------
// Per-pixel: 6 ds_add_f32 to wave-private bins (tv stride 6 -> distinct banks)
// instead of an 8-instance select chain + 50 DPP reductions.
__global__ __launch_bounds__(256) void k1_stats(const float* __restrict__ xv,
                                                const float* __restrict__ xs,
                                                const float* __restrict__ xseed,
                                                const int*  __restrict__ t,
                                                float* __restrict__ pk1) {
    const int b = blockIdx.y, bx = blockIdx.x, tid = threadIdx.x;
    const int wid = tid >> 6;
    __shared__ float bins[4*64];   // [wave][slot]; slots: (tv-1)*6+q for fg, 48/49 for bg
    bins[tid] = 0.f;
    __syncthreads();

    const float* xv_y = xv + (size_t)b*2*P;
    const float* xv_x = xv_y + P;
    const float* xs_y = xs + (size_t)b*2*P;
    const float* xs_x = xs_y + P;
    const float* sdp  = xseed + (size_t)b*P;
    const int*   tb   = t + (size_t)b*P;

    int p0 = bx*K1PX + tid*4;
    float4 vy = *(const float4*)(xv_y + p0);
    float4 vx = *(const float4*)(xv_x + p0);
    float4 sy = *(const float4*)(xs_y + p0);
    float4 sx = *(const float4*)(xs_x + p0);
    float4 se = *(const float4*)(sdp + p0);
    int4   tt = *(const int4*)(tb + p0);

    float* wb = &bins[wid*64];
    #pragma unroll
    for (int j = 0; j < 4; ++j) {
        int pix = p0 + j;
        float ey = fast_tanh((&vy.x)[j]) + (float)(pix >> 10) * (1.0f/1024.0f);
        float ex = fast_tanh((&vx.x)[j]) + (float)(pix & 1023) * (1.0f/1024.0f);
        float gy = (&sy.x)[j], gx = (&sx.x)[j];
        int tv = (&tt.x)[j];
        if (tv == 0) {
            float s = fast_sigmoid((&se.x)[j]);
            atomicAdd(&wb[48], 1.0f);
            atomicAdd(&wb[49], s*s);
        } else {
            int o = (tv - 1)*6;
            atomicAdd(&wb[o+0], 1.0f);
            atomicAdd(&wb[o+1], ey);
            atomicAdd(&wb[o+2], ex);
            atomicAdd(&wb[o+3], gy);
            atomicAdd(&wb[o+4], gx);
            atomicAdd(&wb[o+5], gy*gy + gx*gx);
        }
    }
    __syncthreads();
    if (tid < 50) {
        float s = bins[tid] + bins[64+tid] + bins[128+tid] + bins[192+tid];
        pk1[(size_t)(b*K1B + bx)*64 + tid] = s;   // one coalesced 200B row per block
    }
}

// ---------------- K2: reduce partials + finalize params ----------------
__global__ __launch_bounds__(1024) void k2_finalize(float* __restrict__ wsf,
                                                    const float* __restrict__ pk1,
                                                    float* __restrict__ out) {
    const int tid = threadIdx.x;
    __shared__ float part[16*64];
    __shared__ float ssum[4*64];
    const int v = tid & 63, g = tid >> 6;    // g = 0..15
    const int b = g >> 2, c = g & 3;
    float acc = 0.f;
    const int jbase = b*K1B + c*128;
    #pragma unroll 8
    for (int i = 0; i < 128; ++i) acc += pk1[(size_t)(jbase + i)*64 + v];  // coalesced
    part[g*64 + v] = acc;
    __syncthreads();
    if (tid < 256) {
        int vb = tid & 63, bb = tid >> 6;
        ssum[bb*64+vb] = part[(bb*4+0)*64+vb] + part[(bb*4+1)*64+vb]
                       + part[(bb*4+2)*64+vb] + part[(bb*4+3)*64+vb];
    }
    __syncthreads();
    if (tid < NSEG) {
        int n = tid >> 2, bb = tid & 3;      // seg = n*B + bb = tid
        float cv  = ssum[bb*64 + n*6+0];
        float sey = ssum[bb*64 + n*6+1];
        float sex = ssum[bb*64 + n*6+2];
        float sgy = ssum[bb*64 + n*6+3];
        float sgx = ssum[bb*64 + n*6+4];
        float sq  = ssum[bb*64 + n*6+5];
        float safe = fmaxf(cv, 1.0f);
        float ipy = sgy/safe, ipx = sgx/safe;
        wsf[D_CENY+tid] = sey/safe;
        wsf[D_CENX+tid] = sex/safe;
        wsf[D_PSY+tid]  = expf(10.0f*ipy);
        wsf[D_PSX+tid]  = expf(10.0f*ipx);
        wsf[D_CNT+tid]  = cv;
        wsf[D_SL+tid]   = sq/safe - (ipy*ipy + ipx*ipx);
    } else if (tid < NSEG + B) {
        int bb = tid - NSEG;
        wsf[D_BGL+bb] = ssum[bb*64+49] / fmaxf(ssum[bb*64+48], 1.0f);
    } else if (tid == 40) {
        out[0] = 0.f;
    }
}

// ---------------- K3: LDS histograms, key-0 skipped ----------------
__global__ __launch_bounds__(512) void k3_hist(const float* __restrict__ xv,
                                               const float* __restrict__ xseed,
                                               const int*  __restrict__ t,
                                               const float* __restrict__ wsf,
                                               unsigned* __restrict__ hist_g,
                                               float* __restrict__ fgp) {
    const int strip = blockIdx.x;
    const int b     = blockIdx.y;
    const int tid   = threadIdx.x;
    const int lane  = tid & 63;

    __shared__ unsigned hist[NI*NB];   // 32 KB: pos<<16 | neg
    {
        uint4 z = {0u,0u,0u,0u};
        #pragma unroll
        for (int i = 0; i < 4; ++i) *((uint4*)hist + i*512 + tid) = z;
    }
    __shared__ float spar[4*NI];
    if (tid < 4*NI) {
        int n = tid & (NI-1), q = tid >> 3;
        spar[tid] = wsf[q*32 + n*B + b];   // q: 0=ceny 1=cenx 2=psy 3=psx
    }
    __syncthreads();

    float ceny[NI], cenx[NI], psy[NI], psx[NI], fgn[NI];
    #pragma unroll
    for (int n = 0; n < NI; ++n) {
        ceny[n] = spar[n]; cenx[n] = spar[NI+n];
        psy[n] = spar[2*NI+n]; psx[n] = spar[3*NI+n];
        fgn[n] = 0.f;
    }

    const float* xv_y = xv + (size_t)b*2*P;
    const float* xv_x = xv_y + P;
    const float* sdp  = xseed + (size_t)b*P;
    const int*   tb   = t + (size_t)b*P;
    const int base = strip * STRIP_PX;

    #pragma unroll
    for (int it = 0; it < STRIP_PX/2048; ++it) {   // 2 iters
        int p0 = base + it*2048 + tid*4;
        float4 vy = *(const float4*)(xv_y + p0);
        float4 vx = *(const float4*)(xv_x + p0);
        float4 se = *(const float4*)(sdp + p0);
        int4   tt = *(const int4*)(tb + p0);
        #pragma unroll
        for (int j = 0; j < 4; ++j) {
            int pix = p0 + j;
            float ey = fast_tanh((&vy.x)[j]) + (float)(pix >> 10) * (1.0f/1024.0f);
            float ex = fast_tanh((&vx.x)[j]) + (float)(pix & 1023) * (1.0f/1024.0f);
            int tv = (&tt.x)[j];
            float gown = 0.f;
            #pragma unroll
            for (int n = 0; n < NI; ++n) {
                float dy = ey - ceny[n], dx = ex - cenx[n];
                float g = __expf(-0.5f * (psy[n]*dy*dy + psx[n]*dx*dx));
                bool lab = (tv == n+1);
                float err = lab ? (2.0f - 2.0f*g) : (2.0f*g);
                int key = (int)(err * INV_BW);
                key = key > (NB-1) ? (NB-1) : key;
                // key==0 counts are reconstructed exactly in K4b from totals
                if (key > 0) atomicAdd(&hist[n*NB + key], lab ? 0x10000u : 1u);
                if (lab) gown = g;
            }
            if (tv > 0) {
                float s = fast_sigmoid((&se.x)[j]);
                float d = s - gown;
                float dd = d*d;
                #pragma unroll
                for (int n = 0; n < NI; ++n) fgn[n] += (tv == n+1) ? dd : 0.f;
            }
        }
    }
    __syncthreads();
    // vectorized flush: 4 x uint4 per thread
    #pragma unroll
    for (int i = 0; i < 4; ++i) {
        int lin = i*2048 + tid*4;
        int n = lin >> 10, key = lin & (NB-1);
        uint4 v = *(const uint4*)&hist[lin];
        *(uint4*)&hist_g[((size_t)((n*4 + b)*NSTRIP + strip))*NB + key] = v;
    }
    __shared__ float sfg[NI];
    if (tid < NI) sfg[tid] = 0.f;
    __syncthreads();
    #pragma unroll
    for (int n = 0; n < NI; ++n) {
        float r = wred(fgn[n]);
        if (lane == 63 && r != 0.f) atomicAdd(&sfg[n], r);   // LDS, 8-way max
    }
    __syncthreads();
    if (tid < NI) fgp[tid*512 + b*NSTRIP + strip] = sfg[tid];  // plain store
}

// ---------------- K4a: wide fold of strip histograms (128 blocks) ----------------
__global__ __launch_bounds__(256) void k4a_fold(const unsigned* __restrict__ hist_g,
                                                unsigned* __restrict__ fold) {
    const int seg = blockIdx.x >> 2;                 // NSEG*4 = 128 blocks
    const int key = (blockIdx.x & 3)*256 + threadIdx.x;
    const unsigned* src = hist_g + (size_t)seg*NSTRIP*NB + key;
    unsigned pos = 0u, neg = 0u;
    #pragma unroll 8
    for (int s = 0; s < NSTRIP; ++s) {
        unsigned v = src[(size_t)s*NB];              // coalesced across threads
        pos += v >> 16; neg += v & 0xffffu;
    }
    fold[(size_t)seg*NB + key] = pos;
    fold[(size_t)(NSEG + seg)*NB + key] = neg;
}

// ---------------- K4b: suffix scan + finalize ----------------
__global__ __launch_bounds__(256) void k4b_scan(const unsigned* __restrict__ fold,
                                                const float* __restrict__ wsf,
                                                const float* __restrict__ fgp,
                                                float* __restrict__ out) {
    const int seg = blockIdx.x, tid = threadIdx.x;
    const int n = seg >> 2, b = seg & 3;
    __shared__ float scnt[NSEG];
    if (tid < NSEG) scnt[tid] = wsf[D_CNT + tid];
    __syncthreads();

    if (seg == 0 && tid == 0) {   // sigma loss + background seed loss
        float add = 0.f;
        for (int bb = 0; bb < B; ++bb) {
            int np = 0; float ss = 0.f;
            for (int k = 0; k < NI; ++k) {
                float c = scnt[k*4 + bb];
                if (c > 0.5f) { np++; ss += wsf[D_SL + k*4 + bb]; }
            }
            float npf = fmaxf((float)np, 1.0f);
            add += ss/npf + wsf[D_BGL+bb] / (1.0f + (float)np);
        }
        atomicAdd(out, add * (1.0f/(float)B));
    }

    const float G = scnt[seg];
    if (G < 0.5f) return;   // uniform across block
    int npc = 0;
    #pragma unroll
    for (int k = 0; k < NI; ++k) npc += (scnt[k*4 + b] > 0.5f) ? 1 : 0;

    // fg seed partial reduce (128 strips)
    __shared__ float sfr[128];
    if (tid < 128) sfr[tid] = fgp[n*512 + b*NSTRIP + tid];
    __syncthreads();
    #pragma unroll
    for (int d = 64; d > 0; d >>= 1) {
        if (tid < d) sfr[tid] += sfr[tid + d];
        __syncthreads();
    }
    const float FG = sfr[0];

    // thread t owns keys 4t..4t+3 from the folded arrays
    uint4 pv = *((const uint4*)(fold + (size_t)seg*NB) + tid);
    uint4 nv = *((const uint4*)(fold + (size_t)(NSEG + seg)*NB) + tid);
    unsigned pos4[4] = {pv.x, pv.y, pv.z, pv.w};
    unsigned neg4[4] = {nv.x, nv.y, nv.z, nv.w};
    unsigned tp = pos4[0]+pos4[1]+pos4[2]+pos4[3];
    unsigned tn = neg4[0]+neg4[1]+neg4[2]+neg4[3];

    // suffix (descending-key) inclusive scan over thread totals
    __shared__ unsigned up[256], un[256];
    up[tid] = tp; un[tid] = tn;
    __syncthreads();
    for (int d = 1; d < 256; d <<= 1) {
        unsigned ap = (tid + d < 256) ? up[tid + d] : 0u;
        unsigned an = (tid + d < 256) ? un[tid + d] : 0u;
        __syncthreads();
        up[tid] += ap; un[tid] += an;
        __syncthreads();
    }
    const unsigned TP = up[0], TN = un[0];
    const unsigned Gu = (unsigned)(G + 0.5f);
    const unsigned NEGu = (unsigned)P - Gu;
    unsigned cump = up[tid] - tp;   // counts with key strictly greater
    unsigned cumn = un[tid] - tn;

    const double dG = (double)G;
    double acc = 0.0;
    #pragma unroll
    for (int j = 3; j >= 0; --j) {
        unsigned cp = pos4[j], cn = neg4[j];
        int key = tid*4 + j;
        if (tid == 0 && j == 0) { cp = Gu - TP; cn = NEGu - TN; }  // exact bucket-0
        if (cp | cn) {
            unsigned ep = cump, en = cumn;
            unsigned epi = ep + cp, eni = en + cn;
            double jb = 1.0 - (dG - (double)ep)  / (dG + (double)en);
            double ja = 1.0 - (dG - (double)epi) / (dG + (double)eni);
            acc += (((double)key + 0.5) * (2.0/(double)NB)) * (ja - jb);
        }
        cump += cp; cumn += cn;
    }
    __shared__ double sdd[256];
    sdd[tid] = acc;
    __syncthreads();
    #pragma unroll
    for (int d = 128; d > 0; d >>= 1) {
        if (tid < d) sdd[tid] += sdd[tid + d];
        __syncthreads();
    }
    if (tid == 0) {
        float npf = fmaxf((float)npc, 1.0f);
        float val = (float)sdd[0] / (npf * (float)B)
                  + (FG / G) / ((1.0f + (float)npc) * (float)B);
        atomicAdd(out, val);
    }
}

extern "C" void kernel_launch(void* const* d_in, const int* in_sizes, int n_in,
                              void* d_out, int out_size, void* d_ws, size_t ws_size,
                              hipStream_t stream) {
    (void)in_sizes; (void)n_in; (void)out_size; (void)ws_size;
    const float* xv  = (const float*)d_in[0];
    const float* xs  = (const float*)d_in[1];
    const float* xsd = (const float*)d_in[2];
    const int*   t   = (const int*)d_in[3];
    float* wsf = (float*)d_ws;
    unsigned* hist_g = (unsigned*)d_ws + OFF_HIST;
    unsigned* fold   = (unsigned*)d_ws + OFF_FOLD;
    float* pk1 = wsf + OFF_PK1;
    float* fgp = wsf + OFF_FGP;
    float* out = (float*)d_out;

    k1_stats<<<dim3(K1B, B), 256, 0, stream>>>(xv, xs, xsd, t, pk1);
    k2_finalize<<<1, 1024, 0, stream>>>(wsf, pk1, out);
    k3_hist<<<dim3(NSTRIP, B), 512, 0, stream>>>(xv, xsd, t, wsf, hist_g, fgp);
    k4a_fold<<<NSEG*4, 256, 0, stream>>>(hist_g, fold);
    k4b_scan<<<NSEG, 256, 0, stream>>>(fold, wsf, fgp, out);
}

// Round 9
// 132.872 us; speedup vs baseline: 1.8067x; 1.3656x over previous
//
#include <hip/hip_runtime.h>
#include <math.h>

#define B 4
#define H 512
#define W 1024
#define P (H*W)            // 524288
#define NI 8
#define NSEG 32            // seg = n*B + b
#define NB 512             // histogram buckets over err in [0,2]
#define INV_BW ((float)NB/2.0f)
#define NSTRIP 128
#define STRIP_PX (P/NSTRIP) // 4096
#define K1B 512             // k1 blocks per batch
#define K1PX (P/K1B)        // 1024 px per k1 block

// ---- ws layout (4-byte units) ----
#define D_CENY 0
#define D_CENX 32
#define D_PSY  64
#define D_PSX  96
#define D_CNT  128
#define D_SL   160
#define D_BGL  192          // 4
#define OFF_FGP 256         // NI*512 floats = 16 KB
#define OFF_HIST (256 + NI*512)              // u32: NSEG*NSTRIP*NB = 8 MB
#define OFF_FOLD (OFF_HIST + NSEG*NSTRIP*NB) // u32: 8*NSEG*NB = 512 KB
#define OFF_PK1  OFF_HIST   // pk1 (2048*64 floats = 512 KB) overlaps hist:
                            // k1 writes pk1 -> k2 consumes -> k3 overwrites hist. Safe.

__device__ __forceinline__ float fast_tanh(float x) {
    float e = __expf(2.0f * x);
    return 1.0f - 2.0f / (e + 1.0f);
}
__device__ __forceinline__ float fast_sigmoid(float x) {
    return 1.0f / (1.0f + __expf(-x));
}
template<int CTRL, int RM>
__device__ __forceinline__ float dpp_add(float x) {
    int y = __builtin_amdgcn_update_dpp(0, __float_as_int(x), CTRL, RM, 0xF, true);
    return x + __int_as_float(y);
}
__device__ __forceinline__ float wred(float x) {
    x = dpp_add<0x111, 0xF>(x);   // row_shr:1
    x = dpp_add<0x112, 0xF>(x);   // row_shr:2
    x = dpp_add<0x114, 0xF>(x);   // row_shr:4
    x = dpp_add<0x118, 0xF>(x);   // row_shr:8
    x = dpp_add<0x142, 0xA>(x);   // row_bcast:15
    x = dpp_add<0x143, 0xC>(x);   // row_bcast:31
    return x;                     // lane 63 = wave total
}

// ---------------- K1: per-block partial sums (register acc + DPP, R5-proven) ----
__global__ __launch_bounds__(256) void k1_stats(const float* __restrict__ xv,
                                                const float* __restrict__ xs,
                                                const float* __restrict__ xseed,
                                                const int*  __restrict__ t,
                                                float* __restrict__ pk1) {
    const int b = blockIdx.y, bx = blockIdx.x, tid = threadIdx.x;
    const int lane = tid & 63, wid = tid >> 6;
    const float* xv_y = xv + (size_t)b*2*P;
    const float* xv_x = xv_y + P;
    const float* xs_y = xs + (size_t)b*2*P;
    const float* xs_x = xs_y + P;
    const float* sdp  = xseed + (size_t)b*P;
    const int*   tb   = t + (size_t)b*P;

    float cnt[NI], sey[NI], sex[NI], sgy[NI], sgx[NI], sq[NI];
    #pragma unroll
    for (int n = 0; n < NI; ++n) { cnt[n]=0.f; sey[n]=0.f; sex[n]=0.f; sgy[n]=0.f; sgx[n]=0.f; sq[n]=0.f; }
    float bgc = 0.f, bgs = 0.f;

    int p0 = bx*K1PX + tid*4;
    float4 vy = *(const float4*)(xv_y + p0);
    float4 vx = *(const float4*)(xv_x + p0);
    float4 sy = *(const float4*)(xs_y + p0);
    float4 sx = *(const float4*)(xs_x + p0);
    float4 se = *(const float4*)(sdp + p0);
    int4   tt = *(const int4*)(tb + p0);
    #pragma unroll
    for (int j = 0; j < 4; ++j) {
        int pix = p0 + j;
        float ey = fast_tanh((&vy.x)[j]) + (float)(pix >> 10) * (1.0f/1024.0f);
        float ex = fast_tanh((&vx.x)[j]) + (float)(pix & 1023) * (1.0f/1024.0f);
        float gy = (&sy.x)[j], gx = (&sx.x)[j];
        int tv = (&tt.x)[j];
        if (tv == 0) {
            float s = fast_sigmoid((&se.x)[j]);
            bgc += 1.f; bgs += s*s;
        }
        float q = gy*gy + gx*gx;
        #pragma unroll
        for (int n = 0; n < NI; ++n) {
            float m = (tv == n+1) ? 1.0f : 0.0f;
            cnt[n] += m; sey[n] += m*ey; sex[n] += m*ex;
            sgy[n] += m*gy; sgx[n] += m*gx; sq[n] += m*q;
        }
    }
    __shared__ float sw[4*64];
    #define RED50(val, slot) { float r_ = wred(val); if (lane == 63) sw[wid*64 + (slot)] = r_; }
    #pragma unroll
    for (int n = 0; n < NI; ++n) {
        RED50(cnt[n], n*6+0); RED50(sey[n], n*6+1); RED50(sex[n], n*6+2);
        RED50(sgy[n], n*6+3); RED50(sgx[n], n*6+4); RED50(sq[n],  n*6+5);
    }
    RED50(bgc, 48); RED50(bgs, 49);
    #undef RED50
    __syncthreads();
    if (tid < 50) {
        float s = sw[tid] + sw[64+tid] + sw[128+tid] + sw[192+tid];
        pk1[(size_t)(b*K1B + bx)*64 + tid] = s;   // one coalesced 200B row per block
    }
}

// ---------------- K2: reduce partials + finalize params ----------------
__global__ __launch_bounds__(1024) void k2_finalize(float* __restrict__ wsf,
                                                    const float* __restrict__ pk1,
                                                    float* __restrict__ out) {
    const int tid = threadIdx.x;
    __shared__ float part[16*64];
    __shared__ float ssum[4*64];
    const int v = tid & 63, g = tid >> 6;    // g = 0..15
    const int b = g >> 2, c = g & 3;
    float acc = 0.f;
    const int jbase = b*K1B + c*128;
    #pragma unroll 8
    for (int i = 0; i < 128; ++i) acc += pk1[(size_t)(jbase + i)*64 + v];  // coalesced
    part[g*64 + v] = acc;
    __syncthreads();
    if (tid < 256) {
        int vb = tid & 63, bb = tid >> 6;
        ssum[bb*64+vb] = part[(bb*4+0)*64+vb] + part[(bb*4+1)*64+vb]
                       + part[(bb*4+2)*64+vb] + part[(bb*4+3)*64+vb];
    }
    __syncthreads();
    if (tid < NSEG) {
        int n = tid >> 2, bb = tid & 3;      // seg = n*B + bb = tid
        float cv  = ssum[bb*64 + n*6+0];
        float sey = ssum[bb*64 + n*6+1];
        float sex = ssum[bb*64 + n*6+2];
        float sgy = ssum[bb*64 + n*6+3];
        float sgx = ssum[bb*64 + n*6+4];
        float sq  = ssum[bb*64 + n*6+5];
        float safe = fmaxf(cv, 1.0f);
        float ipy = sgy/safe, ipx = sgx/safe;
        wsf[D_CENY+tid] = sey/safe;
        wsf[D_CENX+tid] = sex/safe;
        wsf[D_PSY+tid]  = expf(10.0f*ipy);
        wsf[D_PSX+tid]  = expf(10.0f*ipx);
        wsf[D_CNT+tid]  = cv;
        wsf[D_SL+tid]   = sq/safe - (ipy*ipy + ipx*ipx);
    } else if (tid < NSEG + B) {
        int bb = tid - NSEG;
        wsf[D_BGL+bb] = ssum[bb*64+49] / fmaxf(ssum[bb*64+48], 1.0f);
    } else if (tid == 40) {
        out[0] = 0.f;
    }
}

// ---------------- K3: LDS histograms (16 KB), key-0 skipped ----------------
__global__ __launch_bounds__(512) void k3_hist(const float* __restrict__ xv,
                                               const float* __restrict__ xseed,
                                               const int*  __restrict__ t,
                                               const float* __restrict__ wsf,
                                               unsigned* __restrict__ hist_g,
                                               float* __restrict__ fgp) {
    const int strip = blockIdx.x;
    const int b     = blockIdx.y;
    const int tid   = threadIdx.x;
    const int lane  = tid & 63;

    __shared__ unsigned hist[NI*NB];   // 16 KB: pos<<16 | neg
    {
        uint4 z = {0u,0u,0u,0u};
        #pragma unroll
        for (int i = 0; i < 2; ++i) *((uint4*)hist + i*512 + tid) = z;
    }
    __shared__ float spar[4*NI];
    if (tid < 4*NI) {
        int n = tid & (NI-1), q = tid >> 3;
        spar[tid] = wsf[q*32 + n*B + b];   // q: 0=ceny 1=cenx 2=psy 3=psx
    }
    __syncthreads();

    float ceny[NI], cenx[NI], psy[NI], psx[NI], fgn[NI];
    #pragma unroll
    for (int n = 0; n < NI; ++n) {
        ceny[n] = spar[n]; cenx[n] = spar[NI+n];
        psy[n] = spar[2*NI+n]; psx[n] = spar[3*NI+n];
        fgn[n] = 0.f;
    }

    const float* xv_y = xv + (size_t)b*2*P;
    const float* xv_x = xv_y + P;
    const float* sdp  = xseed + (size_t)b*P;
    const int*   tb   = t + (size_t)b*P;
    const int base = strip * STRIP_PX;

    #pragma unroll
    for (int it = 0; it < STRIP_PX/2048; ++it) {   // 2 iters
        int p0 = base + it*2048 + tid*4;
        float4 vy = *(const float4*)(xv_y + p0);
        float4 vx = *(const float4*)(xv_x + p0);
        float4 se = *(const float4*)(sdp + p0);
        int4   tt = *(const int4*)(tb + p0);
        #pragma unroll
        for (int j = 0; j < 4; ++j) {
            int pix = p0 + j;
            float ey = fast_tanh((&vy.x)[j]) + (float)(pix >> 10) * (1.0f/1024.0f);
            float ex = fast_tanh((&vx.x)[j]) + (float)(pix & 1023) * (1.0f/1024.0f);
            int tv = (&tt.x)[j];
            float gown = 0.f;
            #pragma unroll
            for (int n = 0; n < NI; ++n) {
                float dy = ey - ceny[n], dx = ex - cenx[n];
                float g = __expf(-0.5f * (psy[n]*dy*dy + psx[n]*dx*dx));
                bool lab = (tv == n+1);
                float err = lab ? (2.0f - 2.0f*g) : (2.0f*g);
                int key = (int)(err * INV_BW);
                key = key > (NB-1) ? (NB-1) : key;
                // key==0 counts are reconstructed exactly in K4b from totals
                if (key > 0) atomicAdd(&hist[n*NB + key], lab ? 0x10000u : 1u);
                if (lab) gown = g;
            }
            if (tv > 0) {
                float s = fast_sigmoid((&se.x)[j]);
                float d = s - gown;
                float dd = d*d;
                #pragma unroll
                for (int n = 0; n < NI; ++n) fgn[n] += (tv == n+1) ? dd : 0.f;
            }
        }
    }
    __syncthreads();
    // vectorized flush: 2 x uint4 per thread
    #pragma unroll
    for (int i = 0; i < 2; ++i) {
        int lin = i*2048 + tid*4;
        int n = lin >> 9, key = lin & (NB-1);
        uint4 v = *(const uint4*)&hist[lin];
        *(uint4*)&hist_g[((size_t)((n*4 + b)*NSTRIP + strip))*NB + key] = v;
    }
    __shared__ float sfg[NI];
    if (tid < NI) sfg[tid] = 0.f;
    __syncthreads();
    #pragma unroll
    for (int n = 0; n < NI; ++n) {
        float r = wred(fgn[n]);
        if (lane == 63 && r != 0.f) atomicAdd(&sfg[n], r);   // LDS, 8-way max
    }
    __syncthreads();
    if (tid < NI) fgp[tid*512 + b*NSTRIP + strip] = sfg[tid];  // plain store
}

// ---------------- K4a: wide fold into 4 strip-quarter partials ----------------
__global__ __launch_bounds__(256) void k4a_fold(const unsigned* __restrict__ hist_g,
                                                unsigned* __restrict__ fold) {
    const int q   = blockIdx.x;          // strip quarter 0..3
    const int seg = blockIdx.y;          // 0..31
    const int tid = threadIdx.x;
    #pragma unroll
    for (int h = 0; h < 2; ++h) {
        int key = h*256 + tid;
        const unsigned* src = hist_g + (size_t)(seg*NSTRIP + q*32)*NB + key;
        unsigned pos = 0u, neg = 0u;
        #pragma unroll 8
        for (int s = 0; s < 32; ++s) {
            unsigned v = src[(size_t)s*NB];          // coalesced across threads
            pos += v >> 16; neg += v & 0xffffu;
        }
        fold[((size_t)q*NSEG + seg)*NB + key] = pos;
        fold[(size_t)4*NSEG*NB + ((size_t)q*NSEG + seg)*NB + key] = neg;
    }
}

// ---------------- K4b: suffix scan + finalize ----------------
__global__ __launch_bounds__(256) void k4b_scan(const unsigned* __restrict__ fold,
                                                const float* __restrict__ wsf,
                                                const float* __restrict__ fgp,
                                                float* __restrict__ out) {
    const int seg = blockIdx.x, tid = threadIdx.x;
    const int n = seg >> 2, b = seg & 3;
    __shared__ float scnt[NSEG];
    if (tid < NSEG) scnt[tid] = wsf[D_CNT + tid];
    __syncthreads();

    if (seg == 0 && tid == 0) {   // sigma loss + background seed loss
        float add = 0.f;
        for (int bb = 0; bb < B; ++bb) {
            int np = 0; float ss = 0.f;
            for (int k = 0; k < NI; ++k) {
                float c = scnt[k*4 + bb];
                if (c > 0.5f) { np++; ss += wsf[D_SL + k*4 + bb]; }
            }
            float npf = fmaxf((float)np, 1.0f);
            add += ss/npf + wsf[D_BGL+bb] / (1.0f + (float)np);
        }
        atomicAdd(out, add * (1.0f/(float)B));
    }

    const float G = scnt[seg];
    if (G < 0.5f) return;   // uniform across block
    int npc = 0;
    #pragma unroll
    for (int k = 0; k < NI; ++k) npc += (scnt[k*4 + b] > 0.5f) ? 1 : 0;

    // fg seed partial reduce (128 strips)
    __shared__ float sfr[128];
    if (tid < 128) sfr[tid] = fgp[n*512 + b*NSTRIP + tid];
    __syncthreads();
    #pragma unroll
    for (int d = 64; d > 0; d >>= 1) {
        if (tid < d) sfr[tid] += sfr[tid + d];
        __syncthreads();
    }
    const float FG = sfr[0];

    // thread t owns keys 2t, 2t+1: sum the 4 quarter-partials
    unsigned pos2[2] = {0u,0u}, neg2[2] = {0u,0u};
    #pragma unroll
    for (int q = 0; q < 4; ++q) {
        uint2 pv = *((const uint2*)(fold + ((size_t)q*NSEG + seg)*NB) + tid);
        uint2 nv = *((const uint2*)(fold + (size_t)4*NSEG*NB + ((size_t)q*NSEG + seg)*NB) + tid);
        pos2[0] += pv.x; pos2[1] += pv.y;
        neg2[0] += nv.x; neg2[1] += nv.y;
    }
    unsigned tp = pos2[0] + pos2[1];
    unsigned tn = neg2[0] + neg2[1];

    // suffix (descending-key) inclusive scan over thread totals
    __shared__ unsigned up[256], un[256];
    up[tid] = tp; un[tid] = tn;
    __syncthreads();
    for (int d = 1; d < 256; d <<= 1) {
        unsigned ap = (tid + d < 256) ? up[tid + d] : 0u;
        unsigned an = (tid + d < 256) ? un[tid + d] : 0u;
        __syncthreads();
        up[tid] += ap; un[tid] += an;
        __syncthreads();
    }
    const unsigned TP = up[0], TN = un[0];
    const unsigned Gu = (unsigned)(G + 0.5f);
    const unsigned NEGu = (unsigned)P - Gu;
    unsigned cump = up[tid] - tp;   // counts with key strictly greater
    unsigned cumn = un[tid] - tn;

    const double dG = (double)G;
    double acc = 0.0;
    #pragma unroll
    for (int j = 1; j >= 0; --j) {
        unsigned cp = pos2[j], cn = neg2[j];
        int key = tid*2 + j;
        if (tid == 0 && j == 0) { cp = Gu - TP; cn = NEGu - TN; }  // exact bucket-0
        if (cp | cn) {
            unsigned ep = cump, en = cumn;
            unsigned epi = ep + cp, eni = en + cn;
            double jb = 1.0 - (dG - (double)ep)  / (dG + (double)en);
            double ja = 1.0 - (dG - (double)epi) / (dG + (double)eni);
            acc += (((double)key + 0.5) * (2.0/(double)NB)) * (ja - jb);
        }
        cump += cp; cumn += cn;
    }
    __shared__ double sdd[256];
    sdd[tid] = acc;
    __syncthreads();
    #pragma unroll
    for (int d = 128; d > 0; d >>= 1) {
        if (tid < d) sdd[tid] += sdd[tid + d];
        __syncthreads();
    }
    if (tid == 0) {
        float npf = fmaxf((float)npc, 1.0f);
        float val = (float)sdd[0] / (npf * (float)B)
                  + (FG / G) / ((1.0f + (float)npc) * (float)B);
        atomicAdd(out, val);
    }
}

extern "C" void kernel_launch(void* const* d_in, const int* in_sizes, int n_in,
                              void* d_out, int out_size, void* d_ws, size_t ws_size,
                              hipStream_t stream) {
    (void)in_sizes; (void)n_in; (void)out_size; (void)ws_size;
    const float* xv  = (const float*)d_in[0];
    const float* xs  = (const float*)d_in[1];
    const float* xsd = (const float*)d_in[2];
    const int*   t   = (const int*)d_in[3];
    float* wsf = (float*)d_ws;
    unsigned* hist_g = (unsigned*)d_ws + OFF_HIST;
    unsigned* fold   = (unsigned*)d_ws + OFF_FOLD;
    float* pk1 = wsf + OFF_PK1;
    float* fgp = wsf + OFF_FGP;
    float* out = (float*)d_out;

    k1_stats<<<dim3(K1B, B), 256, 0, stream>>>(xv, xs, xsd, t, pk1);
    k2_finalize<<<1, 1024, 0, stream>>>(wsf, pk1, out);
    k3_hist<<<dim3(NSTRIP, B), 512, 0, stream>>>(xv, xsd, t, wsf, hist_g, fgp);
    k4a_fold<<<dim3(4, NSEG), 256, 0, stream>>>(hist_g, fold);
    k4b_scan<<<NSEG, 256, 0, stream>>>(fold, wsf, fgp, out);
}

// Round 10
// 127.973 us; speedup vs baseline: 1.8759x; 1.0383x over previous
//
#include <hip/hip_runtime.h>
#include <math.h>

#define B 4
#define H 512
#define W 1024
#define P (H*W)            // 524288
#define NI 8
#define NSEG 32            // seg = n*B + b
#define NB 512             // histogram buckets over err in [0,2]
#define INV_BW ((float)NB/2.0f)
#define NSTRIP 128
#define STRIP_PX (P/NSTRIP) // 4096
#define K1B 128             // k1 blocks per batch
#define K1PX (P/K1B)        // 4096 px per k1 block

// ---- ws layout (4-byte units) ----
#define D_CENY 0
#define D_CENX 32
#define D_PSY  64
#define D_PSX  96
#define D_CNT  128
#define D_SL   160
#define D_K4C  192          // 32 u32 last-block counters (zeroed by k2)
#define OFF_FGP 256         // 9*512 floats (rows 0..7 = fg per inst, row 8 = bg s^2)
#define OFF_HIST (256 + 9*512)               // u32: NSEG*NSTRIP*NB = 8 MB
#define OFF_FOLD (OFF_HIST + NSEG*NSTRIP*NB) // u32: 8*NSEG*NB = 512 KB
#define OFF_PK1  OFF_HIST   // pk1 (512*64 floats = 128 KB) overlaps hist:
                            // k1 writes pk1 -> k2 consumes -> k3 overwrites hist. Safe.

__device__ __forceinline__ float fast_tanh(float x) {
    float e = __expf(2.0f * x);
    return 1.0f - 2.0f / (e + 1.0f);
}
__device__ __forceinline__ float fast_sigmoid(float x) {
    return 1.0f / (1.0f + __expf(-x));
}
template<int CTRL, int RM>
__device__ __forceinline__ float dpp_add(float x) {
    int y = __builtin_amdgcn_update_dpp(0, __float_as_int(x), CTRL, RM, 0xF, true);
    return x + __int_as_float(y);
}
__device__ __forceinline__ float wred(float x) {
    x = dpp_add<0x111, 0xF>(x);   // row_shr:1
    x = dpp_add<0x112, 0xF>(x);   // row_shr:2
    x = dpp_add<0x114, 0xF>(x);   // row_shr:4
    x = dpp_add<0x118, 0xF>(x);   // row_shr:8
    x = dpp_add<0x142, 0xA>(x);   // row_bcast:15
    x = dpp_add<0x143, 0xC>(x);   // row_bcast:31
    return x;                     // lane 63 = wave total
}

// ---------------- K1: per-block partial sums (no xseed; 4 rounds of ILP) ----
__global__ __launch_bounds__(256) void k1_stats(const float* __restrict__ xv,
                                                const float* __restrict__ xs,
                                                const int*  __restrict__ t,
                                                float* __restrict__ pk1) {
    const int b = blockIdx.y, bx = blockIdx.x, tid = threadIdx.x;
    const int lane = tid & 63, wid = tid >> 6;
    const float* xv_y = xv + (size_t)b*2*P;
    const float* xv_x = xv_y + P;
    const float* xs_y = xs + (size_t)b*2*P;
    const float* xs_x = xs_y + P;
    const int*   tb   = t + (size_t)b*P;

    float cnt[NI], sey[NI], sex[NI], sgy[NI], sgx[NI], sq[NI];
    #pragma unroll
    for (int n = 0; n < NI; ++n) { cnt[n]=0.f; sey[n]=0.f; sex[n]=0.f; sgy[n]=0.f; sgx[n]=0.f; sq[n]=0.f; }

    #pragma unroll
    for (int it = 0; it < 4; ++it) {
        int p0 = bx*K1PX + it*1024 + tid*4;
        float4 vy = *(const float4*)(xv_y + p0);
        float4 vx = *(const float4*)(xv_x + p0);
        float4 sy = *(const float4*)(xs_y + p0);
        float4 sx = *(const float4*)(xs_x + p0);
        int4   tt = *(const int4*)(tb + p0);
        #pragma unroll
        for (int j = 0; j < 4; ++j) {
            int pix = p0 + j;
            float ey = fast_tanh((&vy.x)[j]) + (float)(pix >> 10) * (1.0f/1024.0f);
            float ex = fast_tanh((&vx.x)[j]) + (float)(pix & 1023) * (1.0f/1024.0f);
            float gy = (&sy.x)[j], gx = (&sx.x)[j];
            int tv = (&tt.x)[j];
            float q = gy*gy + gx*gx;
            #pragma unroll
            for (int n = 0; n < NI; ++n) {
                float m = (tv == n+1) ? 1.0f : 0.0f;
                cnt[n] += m; sey[n] += m*ey; sex[n] += m*ex;
                sgy[n] += m*gy; sgx[n] += m*gx; sq[n] += m*q;
            }
        }
    }
    __shared__ float sw[4*64];
    #define RED48(val, slot) { float r_ = wred(val); if (lane == 63) sw[wid*64 + (slot)] = r_; }
    #pragma unroll
    for (int n = 0; n < NI; ++n) {
        RED48(cnt[n], n*6+0); RED48(sey[n], n*6+1); RED48(sex[n], n*6+2);
        RED48(sgy[n], n*6+3); RED48(sgx[n], n*6+4); RED48(sq[n],  n*6+5);
    }
    #undef RED48
    __syncthreads();
    if (tid < 48) {
        float s = sw[tid] + sw[64+tid] + sw[128+tid] + sw[192+tid];
        pk1[(size_t)(b*K1B + bx)*64 + tid] = s;   // coalesced row per block
    }
}

// ---------------- K2: reduce partials + finalize params + zero counters ----------------
__global__ __launch_bounds__(1024) void k2_finalize(float* __restrict__ wsf,
                                                    const float* __restrict__ pk1,
                                                    float* __restrict__ out) {
    const int tid = threadIdx.x;
    __shared__ float part[16*64];
    __shared__ float ssum[4*64];
    const int v = tid & 63, g = tid >> 6;    // g = 0..15
    const int b = g >> 2, c = g & 3;
    float acc = 0.f;
    const int jbase = b*K1B + c*32;
    #pragma unroll 8
    for (int i = 0; i < 32; ++i) acc += pk1[(size_t)(jbase + i)*64 + v];  // coalesced
    part[g*64 + v] = acc;
    __syncthreads();
    if (tid < 256) {
        int vb = tid & 63, bb = tid >> 6;
        ssum[bb*64+vb] = part[(bb*4+0)*64+vb] + part[(bb*4+1)*64+vb]
                       + part[(bb*4+2)*64+vb] + part[(bb*4+3)*64+vb];
    }
    __syncthreads();
    if (tid < NSEG) {
        int n = tid >> 2, bb = tid & 3;      // seg = n*B + bb = tid
        float cv  = ssum[bb*64 + n*6+0];
        float sey = ssum[bb*64 + n*6+1];
        float sex = ssum[bb*64 + n*6+2];
        float sgy = ssum[bb*64 + n*6+3];
        float sgx = ssum[bb*64 + n*6+4];
        float sq  = ssum[bb*64 + n*6+5];
        float safe = fmaxf(cv, 1.0f);
        float ipy = sgy/safe, ipx = sgx/safe;
        wsf[D_CENY+tid] = sey/safe;
        wsf[D_CENX+tid] = sex/safe;
        wsf[D_PSY+tid]  = expf(10.0f*ipy);
        wsf[D_PSX+tid]  = expf(10.0f*ipx);
        wsf[D_CNT+tid]  = cv;
        wsf[D_SL+tid]   = sq/safe - (ipy*ipy + ipx*ipx);
    } else if (tid < 64) {
        ((unsigned*)wsf)[D_K4C + (tid - 32)] = 0u;   // zero last-block counters
    } else if (tid == 64) {
        out[0] = 0.f;
    }
}

// ---------------- K3: LDS histograms (16 KB), key-0 skipped; bg s^2 added ----------------
__global__ __launch_bounds__(512) void k3_hist(const float* __restrict__ xv,
                                               const float* __restrict__ xseed,
                                               const int*  __restrict__ t,
                                               const float* __restrict__ wsf,
                                               unsigned* __restrict__ hist_g,
                                               float* __restrict__ fgp) {
    const int strip = blockIdx.x;
    const int b     = blockIdx.y;
    const int tid   = threadIdx.x;
    const int lane  = tid & 63;

    __shared__ unsigned hist[NI*NB];   // 16 KB: pos<<16 | neg
    {
        uint4 z = {0u,0u,0u,0u};
        #pragma unroll
        for (int i = 0; i < 2; ++i) *((uint4*)hist + i*512 + tid) = z;
    }
    __shared__ float spar[4*NI];
    if (tid < 4*NI) {
        int n = tid & (NI-1), q = tid >> 3;
        spar[tid] = wsf[q*32 + n*B + b];   // q: 0=ceny 1=cenx 2=psy 3=psx
    }
    __syncthreads();

    float ceny[NI], cenx[NI], psy[NI], psx[NI], fgn[NI];
    #pragma unroll
    for (int n = 0; n < NI; ++n) {
        ceny[n] = spar[n]; cenx[n] = spar[NI+n];
        psy[n] = spar[2*NI+n]; psx[n] = spar[3*NI+n];
        fgn[n] = 0.f;
    }
    float bgq = 0.f;

    const float* xv_y = xv + (size_t)b*2*P;
    const float* xv_x = xv_y + P;
    const float* sdp  = xseed + (size_t)b*P;
    const int*   tb   = t + (size_t)b*P;
    const int base = strip * STRIP_PX;

    #pragma unroll
    for (int it = 0; it < STRIP_PX/2048; ++it) {   // 2 iters
        int p0 = base + it*2048 + tid*4;
        float4 vy = *(const float4*)(xv_y + p0);
        float4 vx = *(const float4*)(xv_x + p0);
        float4 se = *(const float4*)(sdp + p0);
        int4   tt = *(const int4*)(tb + p0);
        #pragma unroll
        for (int j = 0; j < 4; ++j) {
            int pix = p0 + j;
            float ey = fast_tanh((&vy.x)[j]) + (float)(pix >> 10) * (1.0f/1024.0f);
            float ex = fast_tanh((&vx.x)[j]) + (float)(pix & 1023) * (1.0f/1024.0f);
            int tv = (&tt.x)[j];
            float gown = 0.f;
            #pragma unroll
            for (int n = 0; n < NI; ++n) {
                float dy = ey - ceny[n], dx = ex - cenx[n];
                float g = __expf(-0.5f * (psy[n]*dy*dy + psx[n]*dx*dx));
                bool lab = (tv == n+1);
                float err = lab ? (2.0f - 2.0f*g) : (2.0f*g);
                int key = (int)(err * INV_BW);
                key = key > (NB-1) ? (NB-1) : key;
                // key==0 counts are reconstructed exactly in K4 from totals
                if (key > 0) atomicAdd(&hist[n*NB + key], lab ? 0x10000u : 1u);
                if (lab) gown = g;
            }
            float s = fast_sigmoid((&se.x)[j]);
            if (tv > 0) {
                float d = s - gown;
                float dd = d*d;
                #pragma unroll
                for (int n = 0; n < NI; ++n) fgn[n] += (tv == n+1) ? dd : 0.f;
            } else {
                bgq += s*s;
            }
        }
    }
    __syncthreads();
    // vectorized flush: 2 x uint4 per thread
    #pragma unroll
    for (int i = 0; i < 2; ++i) {
        int lin = i*2048 + tid*4;
        int n = lin >> 9, key = lin & (NB-1);
        uint4 v = *(const uint4*)&hist[lin];
        *(uint4*)&hist_g[((size_t)((n*4 + b)*NSTRIP + strip))*NB + key] = v;
    }
    __shared__ float sfg[NI+1];
    if (tid < NI+1) sfg[tid] = 0.f;
    __syncthreads();
    #pragma unroll
    for (int n = 0; n < NI; ++n) {
        float r = wred(fgn[n]);
        if (lane == 63 && r != 0.f) atomicAdd(&sfg[n], r);   // LDS, 8-way max
    }
    {
        float r = wred(bgq);
        if (lane == 63) atomicAdd(&sfg[NI], r);
    }
    __syncthreads();
    if (tid < NI+1) fgp[tid*512 + b*NSTRIP + strip] = sfg[tid];  // plain store
}

// ---------------- K4: fold + last-block scan + finalize (fused) ----------------
__global__ __launch_bounds__(256) void k4_fused(const unsigned* __restrict__ hist_g,
                                                unsigned* __restrict__ fold,
                                                float* __restrict__ wsf,
                                                const float* __restrict__ fgp,
                                                float* __restrict__ out) {
    const int q = blockIdx.x;            // strip quarter 0..3
    const int seg = blockIdx.y;          // 0..31
    const int tid = threadIdx.x;

    // ---- fold this quarter's 32 strips ----
    #pragma unroll
    for (int h = 0; h < 2; ++h) {
        int key = h*256 + tid;
        const unsigned* src = hist_g + (size_t)(seg*NSTRIP + q*32)*NB + key;
        unsigned pos = 0u, neg = 0u;
        #pragma unroll 8
        for (int s = 0; s < 32; ++s) {
            unsigned v = src[(size_t)s*NB];          // coalesced across threads
            pos += v >> 16; neg += v & 0xffffu;
        }
        fold[((size_t)q*NSEG + seg)*NB + key] = pos;
        fold[(size_t)4*NSEG*NB + ((size_t)q*NSEG + seg)*NB + key] = neg;
    }

    // ---- last-block election (counters zeroed by k2) ----
    __shared__ unsigned slast;
    __syncthreads();     // drains this block's fold stores (vmcnt(0) before barrier)
    if (tid == 0) {
        __threadfence();  // agent-scope release: writeback L2
        unsigned* cnt4 = (unsigned*)wsf + D_K4C;
        slast = __hip_atomic_fetch_add(&cnt4[seg], 1u, __ATOMIC_ACQ_REL,
                                       __HIP_MEMORY_SCOPE_AGENT);
    }
    __syncthreads();
    if (slast != 3u) return;
    __threadfence();      // acquire: invalidate stale clean lines before reading fold

    // ---- scan + finalize (one block per seg) ----
    const int n = seg >> 2, b = seg & 3;
    __shared__ float scnt[NSEG];
    __shared__ float sfr[128];
    __shared__ unsigned up[256], un[256];
    __shared__ double sdd[256];
    if (tid < NSEG) scnt[tid] = wsf[D_CNT + tid];
    __syncthreads();

    if (n == 0) {   // per-batch sigma loss + background seed loss
        if (tid < 128) sfr[tid] = fgp[NI*512 + b*NSTRIP + tid];   // bg s^2 partials
        __syncthreads();
        #pragma unroll
        for (int d = 64; d > 0; d >>= 1) {
            if (tid < d) sfr[tid] += sfr[tid + d];
            __syncthreads();
        }
        if (tid == 0) {
            float bgs = sfr[0];
            int np = 0; float ss = 0.f, csum = 0.f;
            for (int k = 0; k < NI; ++k) {
                float cv = scnt[k*4 + b];
                csum += cv;
                if (cv > 0.5f) { np++; ss += wsf[D_SL + k*4 + b]; }
            }
            float bgc = fmaxf((float)P - csum, 1.0f);
            float bgl = bgs / bgc;
            float npf = fmaxf((float)np, 1.0f);
            atomicAdd(out, (ss/npf + bgl/(1.0f + (float)np)) * (1.0f/(float)B));
        }
        __syncthreads();
    }

    const float G = scnt[seg];
    if (G < 0.5f) return;   // uniform across block
    int npc = 0;
    #pragma unroll
    for (int k = 0; k < NI; ++k) npc += (scnt[k*4 + b] > 0.5f) ? 1 : 0;

    // fg seed partial reduce (128 strips)
    if (tid < 128) sfr[tid] = fgp[n*512 + b*NSTRIP + tid];
    __syncthreads();
    #pragma unroll
    for (int d = 64; d > 0; d >>= 1) {
        if (tid < d) sfr[tid] += sfr[tid + d];
        __syncthreads();
    }
    const float FG = sfr[0];

    // thread t owns keys 2t, 2t+1: sum the 4 quarter-partials
    unsigned pos2[2] = {0u,0u}, neg2[2] = {0u,0u};
    #pragma unroll
    for (int qq = 0; qq < 4; ++qq) {
        uint2 pv = *((const uint2*)(fold + ((size_t)qq*NSEG + seg)*NB) + tid);
        uint2 nv = *((const uint2*)(fold + (size_t)4*NSEG*NB + ((size_t)qq*NSEG + seg)*NB) + tid);
        pos2[0] += pv.x; pos2[1] += pv.y;
        neg2[0] += nv.x; neg2[1] += nv.y;
    }
    unsigned tp = pos2[0] + pos2[1];
    unsigned tn = neg2[0] + neg2[1];

    // suffix (descending-key) inclusive scan over thread totals
    up[tid] = tp; un[tid] = tn;
    __syncthreads();
    for (int d = 1; d < 256; d <<= 1) {
        unsigned ap = (tid + d < 256) ? up[tid + d] : 0u;
        unsigned an = (tid + d < 256) ? un[tid + d] : 0u;
        __syncthreads();
        up[tid] += ap; un[tid] += an;
        __syncthreads();
    }
    const unsigned TP = up[0], TN = un[0];
    const unsigned Gu = (unsigned)(G + 0.5f);
    const unsigned NEGu = (unsigned)P - Gu;
    unsigned cump = up[tid] - tp;   // counts with key strictly greater
    unsigned cumn = un[tid] - tn;

    const double dG = (double)G;
    double acc = 0.0;
    #pragma unroll
    for (int j = 1; j >= 0; --j) {
        unsigned cp = pos2[j], cn = neg2[j];
        int key = tid*2 + j;
        if (tid == 0 && j == 0) { cp = Gu - TP; cn = NEGu - TN; }  // exact bucket-0
        if (cp | cn) {
            unsigned ep = cump, en = cumn;
            unsigned epi = ep + cp, eni = en + cn;
            double jb = 1.0 - (dG - (double)ep)  / (dG + (double)en);
            double ja = 1.0 - (dG - (double)epi) / (dG + (double)eni);
            acc += (((double)key + 0.5) * (2.0/(double)NB)) * (ja - jb);
        }
        cump += cp; cumn += cn;
    }
    sdd[tid] = acc;
    __syncthreads();
    #pragma unroll
    for (int d = 128; d > 0; d >>= 1) {
        if (tid < d) sdd[tid] += sdd[tid + d];
        __syncthreads();
    }
    if (tid == 0) {
        float npf = fmaxf((float)npc, 1.0f);
        float val = (float)sdd[0] / (npf * (float)B)
                  + (FG / G) / ((1.0f + (float)npc) * (float)B);
        atomicAdd(out, val);
    }
}

extern "C" void kernel_launch(void* const* d_in, const int* in_sizes, int n_in,
                              void* d_out, int out_size, void* d_ws, size_t ws_size,
                              hipStream_t stream) {
    (void)in_sizes; (void)n_in; (void)out_size; (void)ws_size;
    const float* xv  = (const float*)d_in[0];
    const float* xs  = (const float*)d_in[1];
    const float* xsd = (const float*)d_in[2];
    const int*   t   = (const int*)d_in[3];
    float* wsf = (float*)d_ws;
    unsigned* hist_g = (unsigned*)d_ws + OFF_HIST;
    unsigned* fold   = (unsigned*)d_ws + OFF_FOLD;
    float* pk1 = wsf + OFF_PK1;
    float* fgp = wsf + OFF_FGP;
    float* out = (float*)d_out;

    k1_stats<<<dim3(K1B, B), 256, 0, stream>>>(xv, xs, t, pk1);
    k2_finalize<<<1, 1024, 0, stream>>>(wsf, pk1, out);
    k3_hist<<<dim3(NSTRIP, B), 512, 0, stream>>>(xv, xsd, t, wsf, hist_g, fgp);
    k4_fused<<<dim3(4, NSEG), 256, 0, stream>>>(hist_g, fold, wsf, fgp, out);
}